// Round 10
// baseline (473.513 us; speedup 1.0000x reference)
//
#include <hip/hip_runtime.h>

typedef __attribute__((ext_vector_type(8))) short short8b;
typedef __attribute__((ext_vector_type(4))) float f32x4;

#define NEG_SENTINEL (-1e30f)
#define MAGIC 0x5A17C0DE
constexpr int NB = 256;  // grid blocks; must all be co-resident (<=256 CUs)

// ---------------- workspace layout (float units) ----------------
constexpr int C_OFF    = 0;        // 2*4096 colsums (zeroed P0)
constexpr int C2_OFF   = 8192;     // 2*4096 c2 (zeroed P0)
constexpr int BAR_CNT  = 16388;    // int: barrier arrival count
constexpr int BAR_GEN  = 16389;    // int: barrier generation
constexpr int BAR_MAG  = 16390;    // int: init magic
constexpr int V_OFF    = 16448;    // 20*128 projected weight vectors
constexpr int NP_OFF   = 19008;    // 20*4096 node projections
constexpr int SRC_OFF  = 100928;   // 2*(4096 src + 4096 dst)
constexpr int RM_OFF   = 117312;   // 2*4096 row max
constexpr int RS_OFF   = 125504;   // 2*4096 row sum
constexpr int XBT_OFF  = 133696;   // x^T bf16 [128][4096] (262144 floats)
constexpr int T_OFF    = 395840;   // 524288 floats: T = P@x
constexpr int TP_OFF   = 920128;   // 4*524288 T partials (8 MB)
constexpr int BM_OFF   = 3017280;  // 2*4096*512B bitmasks (4 MB)
// end: 4065856 floats ~= 15.5 MB

__device__ __forceinline__ unsigned short f2bf(float f) {
  unsigned int u = __float_as_uint(f);
  u += 0x7FFFu + ((u >> 16) & 1u);
  return (unsigned short)(u >> 16);
}
__device__ __forceinline__ float bf2f(unsigned short b) {
  return __uint_as_float(((unsigned int)b) << 16);
}
__device__ __forceinline__ float scrub(float v) {
  unsigned int u = __float_as_uint(v);
  return ((u & 0x7F800000u) == 0x7F800000u) ? 0.f : v;
}

// grid barrier: device-scope generation barrier (all NB blocks co-resident)
__device__ __forceinline__ void gbar(int* ib) {
  __syncthreads();
  if (threadIdx.x == 0) {
    __threadfence();  // flush this block's writes to device scope
    int g = __hip_atomic_load(&ib[BAR_GEN], __ATOMIC_RELAXED, __HIP_MEMORY_SCOPE_AGENT);
    int a = __hip_atomic_fetch_add(&ib[BAR_CNT], 1, __ATOMIC_ACQ_REL, __HIP_MEMORY_SCOPE_AGENT);
    if (a == NB - 1) {
      __hip_atomic_store(&ib[BAR_CNT], 0, __ATOMIC_RELAXED, __HIP_MEMORY_SCOPE_AGENT);
      __hip_atomic_store(&ib[BAR_GEN], g + 1, __ATOMIC_RELEASE, __HIP_MEMORY_SCOPE_AGENT);
    } else {
      while (__hip_atomic_load(&ib[BAR_GEN], __ATOMIC_ACQUIRE, __HIP_MEMORY_SCOPE_AGENT) == g)
        __builtin_amdgcn_s_sleep(2);
    }
  }
  __syncthreads();
}

__global__ __launch_bounds__(256, 1) void k_all(
    const void* __restrict__ x, const void* __restrict__ Lup,
    const void* __restrict__ Ldown, const void* __restrict__ P,
    const void* __restrict__ w_irr, const void* __restrict__ w_sol,
    const void* __restrict__ w_har, const void* __restrict__ att_irr,
    const void* __restrict__ att_sol, float* __restrict__ ws,
    void* __restrict__ outv) {
  __shared__ __align__(16) unsigned char smem[69632];
  int* ib = (int*)ws;
  const int bid = blockIdx.x, t = threadIdx.x;

  // barrier init (block 0) — others will spin on magic before first gbar
  if (bid == 0 && t == 0) {
    __hip_atomic_store(&ib[BAR_CNT], 0, __ATOMIC_RELAXED, __HIP_MEMORY_SCOPE_AGENT);
    __hip_atomic_store(&ib[BAR_GEN], 0, __ATOMIC_RELAXED, __HIP_MEMORY_SCOPE_AGENT);
    __threadfence();
    __hip_atomic_store(&ib[BAR_MAG], MAGIC, __ATOMIC_RELEASE, __HIP_MEMORY_SCOPE_AGENT);
  }

  // ---- per-block dtype sniff (no cross-block comm needed) ----
  int flag;
  {
    int* sd = (int*)smem;
    unsigned int ef = (((const unsigned int*)x)[t & 127] >> 7) & 0xFFu;
    sd[t] = (ef >= 100u && ef <= 150u) ? 1 : 0;
    __syncthreads();
    for (int d = 128; d > 0; d >>= 1) { if (t < d) sd[t] += sd[t + d]; __syncthreads(); }
    flag = (sd[0] >= 192) ? 1 : 0;  // doubled count (two copies of 128 words)
    __syncthreads();
  }

  // ================= P0: vvec (blocks 0-19) + zero C/C2 (blocks 64-127) ====
  if (bid < 20 && t < 128) {
    int b = bid / 10, rem = bid % 10, j = rem / 5, tt = rem % 5;
    const void* Wv = (b == 0 ? w_irr : w_sol);
    const void* Av = (b == 0 ? att_irr : att_sol);
    float s = 0.f;
    if (flag) {
      const unsigned short* Wr = (const unsigned short*)Wv + (size_t)j * 16384 + (size_t)t * 128;
      const unsigned short* Ar = (const unsigned short*)Av + tt * 128;
      for (int o = 0; o < 128; o += 8) {
        uint4 wq = *(const uint4*)(Wr + o);
        unsigned int ww[4] = {wq.x, wq.y, wq.z, wq.w};
        float cf[8];
        if (tt < 4) {
          uint4 aq = *(const uint4*)(Ar + o);
          unsigned int aa[4] = {aq.x, aq.y, aq.z, aq.w};
#pragma unroll
          for (int u = 0; u < 4; ++u) {
            cf[2 * u] = bf2f((unsigned short)(aa[u] & 0xFFFFu));
            cf[2 * u + 1] = bf2f((unsigned short)(aa[u] >> 16));
          }
        } else {
#pragma unroll
          for (int e = 0; e < 8; ++e) cf[e] = 1.0f;
        }
#pragma unroll
        for (int u = 0; u < 4; ++u) {
          s += bf2f((unsigned short)(ww[u] & 0xFFFFu)) * cf[2 * u];
          s += bf2f((unsigned short)(ww[u] >> 16)) * cf[2 * u + 1];
        }
      }
    } else {
      const float* Wr = (const float*)Wv + (size_t)j * 16384 + (size_t)t * 128;
      const float* Ar = (const float*)Av + tt * 128;
      for (int o = 0; o < 128; o += 4) {
        float4 wq = *(const float4*)(Wr + o);
        float4 aq = {1.f, 1.f, 1.f, 1.f};
        if (tt < 4) aq = *(const float4*)(Ar + o);
        s += wq.x * aq.x + wq.y * aq.y + wq.z * aq.z + wq.w * aq.w;
      }
    }
    ws[V_OFF + bid * 128 + t] = s;
  }
  if (bid >= 64 && bid < 128) ws[(bid - 64) * 256 + t] = 0.f;  // C + C2 = 16384 floats

  // wait for barrier init, then grid barrier #1
  if (t == 0) {
    while (__hip_atomic_load(&ib[BAR_MAG], __ATOMIC_ACQUIRE, __HIP_MEMORY_SCOPE_AGENT) != MAGIC)
      __builtin_amdgcn_s_sleep(2);
  }
  __syncthreads();
  gbar(ib);

  // ================= P1: prep (blocks 0-63) | bitmask compress (64-255) ====
  if (bid < 64) {
    float* ldsx = (float*)smem;              // 64*130 floats
    float* ldsv = (float*)(smem + 33280);    // 2560 floats
    float* ldsp = (float*)(smem + 43520);    // 4*1280 floats
    float* npl  = (float*)(smem + 64000);    // 1280 floats
    int nb = bid * 64;
    for (int q = 0; q < 16; ++q) {
      int idx = q * 256 + t;
      int row = idx >> 6, cp = idx & 63;
      float vx, vy;
      if (flag) {
        unsigned int u = ((const unsigned int*)x)[(size_t)(nb + row) * 64 + cp];
        vx = bf2f((unsigned short)(u & 0xFFFFu));
        vy = bf2f((unsigned short)(u >> 16));
      } else {
        float2 v = ((const float2*)x)[(size_t)(nb + row) * 64 + cp];
        vx = v.x; vy = v.y;
      }
      ldsx[row * 130 + cp * 2] = vx;
      ldsx[row * 130 + cp * 2 + 1] = vy;
    }
    for (int q = 0; q < 10; ++q) { int idx = q * 256 + t; ldsv[idx] = ws[V_OFF + idx]; }
    __syncthreads();
    unsigned short* xbT = (unsigned short*)(ws + XBT_OFF);
    for (int q = 0; q < 32; ++q) {
      int idx = q * 256 + t;
      int c = idx >> 6, n = idx & 63;
      xbT[(size_t)c * 4096 + nb + n] = f2bf(ldsx[n * 130 + c]);
    }
    int row = t & 63, qq = t >> 6, i0 = qq * 32;
    float acc[20];
#pragma unroll
    for (int k = 0; k < 20; ++k) acc[k] = 0.f;
    for (int i = i0; i < i0 + 32; i += 2) {
      float2 xv = *(const float2*)&ldsx[row * 130 + i];
#pragma unroll
      for (int k = 0; k < 20; ++k) {
        float2 vk = *(const float2*)&ldsv[k * 128 + i];
        acc[k] += xv.x * vk.x + xv.y * vk.y;
      }
    }
#pragma unroll
    for (int k = 0; k < 20; ++k) ldsp[qq * 1280 + row * 20 + k] = acc[k];
    __syncthreads();
    for (int rep = 0; rep < 5; ++rep) {
      int idx = rep * 256 + t;
      int k = idx >> 6, rr = idx & 63;
      float s = ldsp[rr * 20 + k] + ldsp[1280 + rr * 20 + k] +
                ldsp[2560 + rr * 20 + k] + ldsp[3840 + rr * 20 + k];
      npl[k * 64 + rr] = s;
      ws[NP_OFF + (size_t)k * 4096 + nb + rr] = s;
    }
    __syncthreads();
    {
      int b = t >> 7, j = (t >> 6) & 1, kind = (t >> 5) & 1, q = t & 31;
      int bl = q * 2;
      int r = j * 2048 + (nb >> 1) + q;
      int kidx = b * 10 + j * 5 + kind * 2;
      float val = npl[kidx * 64 + bl] + npl[(kidx + 1) * 64 + bl + 1];
      ws[SRC_OFF + b * 8192 + kind * 4096 + r] = val;
    }
  } else {
    // bitmask: out uint4 u covers 128 cols; bit k of byte j = col 8j+k nonzero
    unsigned char* bm = (unsigned char*)(ws + BM_OFF);
    for (int u = (bid - 64) * 256 + t; u < 262144; u += 192 * 256) {
      int mb = u >> 17;
      int rem = u & 131071;
      const void* mask = mb ? Lup : Ldown;
      unsigned int ob[4];
      if (flag) {
        const uint4* in4 = (const uint4*)mask + (size_t)rem * 16;
#pragma unroll
        for (int w4 = 0; w4 < 4; ++w4) {
          unsigned int byts = 0;
#pragma unroll
          for (int bb = 0; bb < 4; ++bb) {
            uint4 v = in4[w4 * 4 + bb];
            unsigned int by = 0;
            by |= ((v.x & 0xFFFFu) != 0u ? 1u : 0u) << 0;
            by |= ((v.x >> 16) != 0u ? 1u : 0u) << 1;
            by |= ((v.y & 0xFFFFu) != 0u ? 1u : 0u) << 2;
            by |= ((v.y >> 16) != 0u ? 1u : 0u) << 3;
            by |= ((v.z & 0xFFFFu) != 0u ? 1u : 0u) << 4;
            by |= ((v.z >> 16) != 0u ? 1u : 0u) << 5;
            by |= ((v.w & 0xFFFFu) != 0u ? 1u : 0u) << 6;
            by |= ((v.w >> 16) != 0u ? 1u : 0u) << 7;
            byts |= by << (8 * bb);
          }
          ob[w4] = byts;
        }
      } else {
        const uint4* in4 = (const uint4*)mask + (size_t)rem * 32;
#pragma unroll
        for (int w4 = 0; w4 < 4; ++w4) {
          unsigned int byts = 0;
#pragma unroll
          for (int bb = 0; bb < 4; ++bb) {
            uint4 v0 = in4[w4 * 8 + bb * 2], v1 = in4[w4 * 8 + bb * 2 + 1];
            unsigned int by = (v0.x != 0u ? 1u : 0u) | ((v0.y != 0u ? 1u : 0u) << 1) |
                              ((v0.z != 0u ? 1u : 0u) << 2) | ((v0.w != 0u ? 1u : 0u) << 3) |
                              ((v1.x != 0u ? 1u : 0u) << 4) | ((v1.y != 0u ? 1u : 0u) << 5) |
                              ((v1.z != 0u ? 1u : 0u) << 6) | ((v1.w != 0u ? 1u : 0u) << 7);
            byts |= by << (8 * bb);
          }
          ob[w4] = byts;
        }
      }
      uint4 o; o.x = ob[0]; o.y = ob[1]; o.z = ob[2]; o.w = ob[3];
      ((uint4*)bm)[u] = o;
    }
  }
  gbar(ib);

  // ================= P2: soft+colsum (32 rows/block), then gemm1 ===========
  {
    const unsigned char* bm = (const unsigned char*)(ws + BM_OFF);
    int wid = t >> 6, l = t & 63;
    for (int rr = 0; rr < 8; ++rr) {
      int GR = bid * 32 + wid * 8 + rr;
      int b = GR >> 12, r = GR & 4095;
      unsigned long long hm =
          ((const unsigned long long*)(bm + ((size_t)b * 4096 + r) * 512))[l];
      const float* srcp = ws + SRC_OFF + b * 8192;
      const float* dstp = srcp + 4096;
      float srcr = srcp[r];
      float ev[8]; int mv[8]; int nh = 0;
      float mx = NEG_SENTINEL, sm = 0.f;
      unsigned long long mm = hm;
      while (mm) {
        int bit = __builtin_ctzll(mm); mm &= mm - 1;
        int m = l * 64 + bit;
        float e = srcr + dstp[m];
        e = (e >= 0.f) ? e : 0.01f * e;
        if (nh < 8) { ev[nh] = e; mv[nh] = m; }
        ++nh;
        if (e > mx) { sm = sm * __expf(mx - e) + 1.f; mx = e; }
        else        { sm += __expf(e - mx); }
      }
      for (int d = 1; d < 64; d <<= 1) {
        float om = __shfl_xor(mx, d);
        float os = __shfl_xor(sm, d);
        float M = fmaxf(mx, om);
        sm = sm * __expf(mx - M) + os * __expf(om - M);
        mx = M;
      }
      if (l == 0) {
        ws[RM_OFF + b * 4096 + r] = mx;
        ws[RS_OFF + b * 4096 + r] = sm;
      }
      float inv = 1.0f / sm;
      int cap = (nh < 8) ? nh : 8;
      for (int i = 0; i < cap; ++i)
        atomicAdd(&ws[C_OFF + b * 4096 + mv[i]], __expf(ev[i] - mx) * inv);
      if (nh > 8) {
        int skip = 8;
        mm = hm;
        while (mm) {
          int bit = __builtin_ctzll(mm); mm &= mm - 1;
          if (skip > 0) { --skip; continue; }
          int m = l * 64 + bit;
          float e = srcr + dstp[m];
          e = (e >= 0.f) ? e : 0.01f * e;
          atomicAdd(&ws[C_OFF + b * 4096 + m], __expf(e - mx) * inv);
        }
      }
    }
  }
  __syncthreads();
  {  // gemm1: 64 M-tiles x 4 K-splits
    unsigned short* a_lds = (unsigned short*)smem;             // 64*40
    unsigned short* b_lds = (unsigned short*)(smem + 5120);    // 128*40
    const unsigned short* xbT = (const unsigned short*)(ws + XBT_OFF);
    const int mt = bid & 63, ks = bid >> 6;
    const int mb = mt * 64;
    const int w = t >> 6, l = t & 63, quad = l >> 4, lr = l & 15;
    f32x4 acc[8] = {};
    const int arow = t >> 2, akq = (t & 3) << 3;
    const int bn = t >> 1, bh = (t & 1) << 4;
    const int k0 = ks * 1024;
    uint4 aU, bU0, bU1;
#define LOADT(IT)                                                              \
  {                                                                            \
    const int kb = k0 + (IT) * 32;                                             \
    if (flag) {                                                                \
      aU = *(const uint4*)((const unsigned short*)P +                          \
                           (size_t)(mb + arow) * 4096 + kb + akq);             \
    } else {                                                                   \
      const float* pa = (const float*)P + (size_t)(mb + arow) * 4096 + kb + akq; \
      float4 f0 = *(const float4*)pa;                                          \
      float4 f1 = *(const float4*)(pa + 4);                                    \
      unsigned short uu[8] = {f2bf(f0.x), f2bf(f0.y), f2bf(f0.z), f2bf(f0.w),  \
                              f2bf(f1.x), f2bf(f1.y), f2bf(f1.z), f2bf(f1.w)}; \
      aU = *(const uint4*)uu;                                                  \
    }                                                                          \
    const unsigned short* src = xbT + (size_t)bn * 4096 + kb + bh;             \
    bU0 = *(const uint4*)src;                                                  \
    bU1 = *(const uint4*)(src + 8);                                            \
  }
    LOADT(0);
    for (int it = 0; it < 32; ++it) {
      *(uint4*)&a_lds[arow * 40 + akq] = aU;
      *(uint4*)&b_lds[bn * 40 + bh] = bU0;
      *(uint4*)&b_lds[bn * 40 + bh + 8] = bU1;
      __syncthreads();
      if (it < 31) LOADT(it + 1);
      short8b af = *(short8b*)&a_lds[(w * 16 + lr) * 40 + quad * 8];
#pragma unroll
      for (int nt = 0; nt < 8; ++nt) {
        short8b bf = *(short8b*)&b_lds[(nt * 16 + lr) * 40 + quad * 8];
        acc[nt] = __builtin_amdgcn_mfma_f32_16x16x32_bf16(af, bf, acc[nt], 0, 0, 0);
      }
      if (it < 31) __syncthreads();
    }
#undef LOADT
    float* Tp = ws + TP_OFF + (size_t)ks * 524288;
#pragma unroll
    for (int nt = 0; nt < 8; ++nt)
#pragma unroll
      for (int rr = 0; rr < 4; ++rr) {
        int row = mb + w * 16 + quad * 4 + rr;
        int col = nt * 16 + lr;
        Tp[(size_t)row * 128 + col] = acc[nt][rr];
      }
  }
  gbar(ib);

  // ================= P3: c2 (32 rows/block) + T partial-sum ================
  {
    const unsigned char* bm = (const unsigned char*)(ws + BM_OFF);
    int wid = t >> 6, l = t & 63;
    for (int rr = 0; rr < 8; ++rr) {
      int GR = bid * 32 + wid * 8 + rr;
      int b = GR >> 12, r = GR & 4095;
      unsigned long long hm =
          ((const unsigned long long*)(bm + ((size_t)b * 4096 + r) * 512))[l];
      const float* srcp = ws + SRC_OFF + b * 8192;
      const float* dstp = srcp + 4096;
      float srcr = srcp[r];
      float rm = ws[RM_OFF + b * 4096 + r];
      float w = ws[C_OFF + b * 4096 + r] / ws[RS_OFF + b * 4096 + r];
      while (hm) {
        int bit = __builtin_ctzll(hm); hm &= hm - 1;
        int m = l * 64 + bit;
        float e = srcr + dstp[m];
        e = (e >= 0.f) ? e : 0.01f * e;
        atomicAdd(&ws[C2_OFF + b * 4096 + m], __expf(e - rm) * w);
      }
    }
    const float4* tp = (const float4*)(ws + TP_OFF);
    float4* T4 = (float4*)(ws + T_OFF);
    for (int k = t; k < 512; k += 256) {
      size_t i4 = (size_t)bid * 512 + k;
      float4 s0 = tp[i4], s1 = tp[131072 + i4], s2 = tp[262144 + i4], s3 = tp[393216 + i4];
      float4 s;
      s.x = s0.x + s1.x + s2.x + s3.x;
      s.y = s0.y + s1.y + s2.y + s3.y;
      s.z = s0.z + s1.z + s2.z + s3.z;
      s.w = s0.w + s1.w + s2.w + s3.w;
      T4[i4] = s;
    }
  }
  gbar(ib);

  // ================= P4: redundant scalar + gemm2 ==========================
  float scal;
  {
    double* sd = (double*)(smem + 8192);
    double acc = 0.0;
    for (int m = t; m < 8192; m += 256) {
      int b = m >> 12, mm = m & 4095;
      float c1 = scrub(ws[C_OFF + b * 4096 + mm]);
      float c2 = scrub(ws[C2_OFF + b * 4096 + mm]);
      float h0 = scrub(ws[NP_OFF + (b * 10 + 4) * 4096 + mm]);
      float h1 = scrub(ws[NP_OFF + (b * 10 + 9) * 4096 + mm]);
      acc += (double)c1 * (double)h0 + (double)c2 * (double)h1;
    }
    sd[t] = acc;
    __syncthreads();
    for (int s = 128; s > 0; s >>= 1) { if (t < s) sd[t] += sd[t + s]; __syncthreads(); }
    scal = (float)sd[0];
    __syncthreads();
  }
  {
    float* tl = (float*)smem;  // 16*128
    int rb = bid * 16;
    const float4* T4 = (const float4*)(ws + T_OFF);
    for (int q = 0; q < 2; ++q) {
      int vi = q * 256 + t;
      ((float4*)tl)[vi] = T4[(size_t)rb * 32 + vi];
    }
    __syncthreads();
    int col = t & 127, rg = t >> 7;
    int r0 = rg * 8;
    float acc[8] = {};
    for (int k = 0; k < 128; k += 4) {
      float w0, w1, w2, w3;
      if (flag) {
        const unsigned short* W16 = (const unsigned short*)w_har;
        w0 = bf2f(W16[(k + 0) * 128 + col]); w1 = bf2f(W16[(k + 1) * 128 + col]);
        w2 = bf2f(W16[(k + 2) * 128 + col]); w3 = bf2f(W16[(k + 3) * 128 + col]);
      } else {
        const float* W32 = (const float*)w_har;
        w0 = W32[(k + 0) * 128 + col]; w1 = W32[(k + 1) * 128 + col];
        w2 = W32[(k + 2) * 128 + col]; w3 = W32[(k + 3) * 128 + col];
      }
#pragma unroll
      for (int rr = 0; rr < 8; ++rr) {
        float4 tv = *(const float4*)&tl[(r0 + rr) * 128 + k];
        acc[rr] += tv.x * w0 + tv.y * w1 + tv.z * w2 + tv.w * w3;
      }
    }
    float s = scrub(scal);
#pragma unroll
    for (int rr = 0; rr < 8; ++rr) {
      size_t oi = (size_t)(rb + r0 + rr) * 128 + col;
      float v = s + acc[rr];
      if (flag) ((unsigned short*)outv)[oi] = f2bf(v);
      else      ((float*)outv)[oi] = v;
    }
  }
}

extern "C" void kernel_launch(void* const* d_in, const int* in_sizes, int n_in,
                              void* d_out, int out_size, void* d_ws, size_t ws_size,
                              hipStream_t stream) {
  k_all<<<NB, 256, 0, stream>>>(d_in[0], d_in[1], d_in[2], d_in[3], d_in[4],
                                d_in[5], d_in[6], d_in[7], d_in[8],
                                (float*)d_ws, d_out);
}